// Round 1
// baseline (492.210 us; speedup 1.0000x reference)
//
#include <hip/hip_runtime.h>

#define T_TOK 1024
#define Dm 768
#define Hm 3072
#define NE 8

typedef __attribute__((ext_vector_type(8))) short short8;
typedef __attribute__((ext_vector_type(4))) float f32x4;

__device__ __forceinline__ unsigned short f2bf(float f) {
  unsigned u = __builtin_bit_cast(unsigned, f);
  u += 0x7fffu + ((u >> 16) & 1u);
  return (unsigned short)(u >> 16);
}

// ---------------- Router: logits = x @ Wr^T, top-2, softmax, compact ----------------
__global__ __launch_bounds__(256) void router_kernel(
    const float* __restrict__ x, const float* __restrict__ Wr,
    int* __restrict__ counts, int* __restrict__ tlist, float* __restrict__ glist) {
  __shared__ float sWr[NE * Dm];  // 24 KB
  for (int i = threadIdx.x; i < NE * Dm; i += 256) sWr[i] = Wr[i];
  __syncthreads();
  const int wave = threadIdx.x >> 6, lane = threadIdx.x & 63;
  const int t = blockIdx.x * 4 + wave;
  float acc[NE];
#pragma unroll
  for (int e = 0; e < NE; e++) acc[e] = 0.f;
  for (int d = lane; d < Dm; d += 64) {
    float xv = x[t * Dm + d];
#pragma unroll
    for (int e = 0; e < NE; e++) acc[e] += xv * sWr[e * Dm + d];
  }
#pragma unroll
  for (int e = 0; e < NE; e++) {
#pragma unroll
    for (int off = 32; off > 0; off >>= 1) acc[e] += __shfl_down(acc[e], off);
  }
  if (lane == 0) {
    int i0 = 0; float v0 = acc[0];
#pragma unroll
    for (int e = 1; e < NE; e++) if (acc[e] > v0) { v0 = acc[e]; i0 = e; }
    int i1 = -1; float v1 = -1e30f;
#pragma unroll
    for (int e = 0; e < NE; e++) if (e != i0 && acc[e] > v1) { v1 = acc[e]; i1 = e; }
    float g0 = 1.f / (1.f + expf(v1 - v0));
    float g1 = 1.f - g0;
    int p0 = atomicAdd(&counts[i0], 1);
    tlist[i0 * T_TOK + p0] = t; glist[i0 * T_TOK + p0] = g0;
    int p1 = atomicAdd(&counts[i1], 1);
    tlist[i1 * T_TOK + p1] = t; glist[i1 * T_TOK + p1] = g1;
  }
}

__global__ void prefix_kernel(const int* __restrict__ counts, int* __restrict__ bases) {
  if (threadIdx.x == 0) {
    int s = 0;
    for (int e = 0; e < NE; e++) { bases[e] = s; s += counts[e]; }
  }
}

// ---------------- Unified B^T-layout bf16 MFMA GEMM, 128x128 tile, BK=64 ----------------
// MODE 0: expert GEMM1  h = relu(gather(x) @ W1[e]^T + b1[e])      -> hbuf (bf16, packed rows)
// MODE 1: expert GEMM2  moe += gate * (h @ W2[e]^T + b2[e])        -> atomicAdd into moe
// MODE 2: shared GEMM1  hs = relu(x @ sW1^T + sb1)                 -> hsbuf (bf16)
// MODE 3: shared GEMM2  out = moe + 0.2*(hs @ sW2^T + sb2)         -> d_out
template <int MODE>
__global__ __launch_bounds__(256) void moe_gemm(
    const float* __restrict__ Afp, const unsigned short* __restrict__ Abf,
    const float* __restrict__ Ball, const float* __restrict__ ball,
    unsigned short* __restrict__ obf, float* __restrict__ moe, float* __restrict__ outp,
    const int* __restrict__ counts, const int* __restrict__ bases,
    const int* __restrict__ tlist, const float* __restrict__ glist) {
  constexpr int Kdim = (MODE == 0 || MODE == 2) ? Dm : Hm;
  constexpr int Ndim = (MODE == 0 || MODE == 2) ? Hm : Dm;
  constexpr bool AF32 = (MODE == 0 || MODE == 2);
  constexpr bool EXP = (MODE <= 1);

  const int e = EXP ? blockIdx.z : 0;
  const int Ne = EXP ? counts[e] : T_TOK;
  const int m0 = blockIdx.y * 128;
  if (m0 >= Ne) return;
  const int n0 = blockIdx.x * 128;

  const float* B = Ball + (size_t)e * Kdim * Ndim;
  const float* bias = ball + (size_t)e * Ndim;

  __shared__ unsigned short sA[128][72];
  __shared__ unsigned short sB[128][72];

  const int tid = threadIdx.x;
  const int lane = tid & 63;
  const int wid = tid >> 6;
  const int wr = wid >> 1, wc = wid & 1;

  // Precompute per-thread A/B row pointers (constant over K loop)
  const float* aRowF[8];
  const unsigned short* aRowB[4];
  if constexpr (AF32) {
#pragma unroll
    for (int c = 0; c < 8; c++) {
      int gi = m0 + c * 16 + (tid >> 4);
      if constexpr (MODE == 0) {
        int si = gi < Ne ? gi : Ne - 1;
        int tok = tlist[e * T_TOK + si];
        aRowF[c] = Afp + (size_t)tok * Dm;
      } else {
        aRowF[c] = Afp + (size_t)gi * Dm;
      }
    }
  } else {
#pragma unroll
    for (int c = 0; c < 4; c++) {
      int gi = m0 + c * 32 + (tid >> 3);
      if constexpr (MODE == 1) {
        int si = gi < Ne ? gi : Ne - 1;
        aRowB[c] = Abf + (size_t)(bases[e] + si) * Hm;
      } else {
        aRowB[c] = Abf + (size_t)gi * Hm;
      }
    }
  }
  const float* bRow[8];
#pragma unroll
  for (int c = 0; c < 8; c++) {
    bRow[c] = B + (size_t)(n0 + c * 16 + (tid >> 4)) * Kdim;
  }

  f32x4 acc[4][4];
#pragma unroll
  for (int m = 0; m < 4; m++)
#pragma unroll
    for (int n = 0; n < 4; n++) acc[m][n] = (f32x4)0.0f;

  const int colF = (tid & 15) * 4;   // f32 staging column (4 elems)
  const int colB8 = (tid & 7) * 8;   // bf16 staging column (8 elems)
  const int frow = lane & 15;
  const int fk = (lane >> 4) * 8;

  for (int k0 = 0; k0 < Kdim; k0 += 64) {
    // ---- stage A tile (128 x 64) ----
    if constexpr (AF32) {
#pragma unroll
      for (int c = 0; c < 8; c++) {
        const float4 v = *(const float4*)(aRowF[c] + k0 + colF);
        int r = c * 16 + (tid >> 4);
        unsigned p0 = (unsigned)f2bf(v.x) | ((unsigned)f2bf(v.y) << 16);
        unsigned p1 = (unsigned)f2bf(v.z) | ((unsigned)f2bf(v.w) << 16);
        *(uint2*)&sA[r][colF] = make_uint2(p0, p1);
      }
    } else {
#pragma unroll
      for (int c = 0; c < 4; c++) {
        const uint4 v = *(const uint4*)(aRowB[c] + k0 + colB8);
        int r = c * 32 + (tid >> 3);
        *(uint4*)&sA[r][colB8] = v;
      }
    }
    // ---- stage B tile (128 x 64), always f32 source ----
#pragma unroll
    for (int c = 0; c < 8; c++) {
      const float4 v = *(const float4*)(bRow[c] + k0 + colF);
      int r = c * 16 + (tid >> 4);
      unsigned p0 = (unsigned)f2bf(v.x) | ((unsigned)f2bf(v.y) << 16);
      unsigned p1 = (unsigned)f2bf(v.z) | ((unsigned)f2bf(v.w) << 16);
      *(uint2*)&sB[r][colF] = make_uint2(p0, p1);
    }
    __syncthreads();
    // ---- MFMA over BK=64 (two K=32 sub-steps) ----
#pragma unroll
    for (int kk = 0; kk < 2; kk++) {
      short8 af[4], bf[4];
#pragma unroll
      for (int m = 0; m < 4; m++)
        af[m] = *(const short8*)&sA[wr * 64 + m * 16 + frow][kk * 32 + fk];
#pragma unroll
      for (int n = 0; n < 4; n++)
        bf[n] = *(const short8*)&sB[wc * 64 + n * 16 + frow][kk * 32 + fk];
#pragma unroll
      for (int m = 0; m < 4; m++)
#pragma unroll
        for (int n = 0; n < 4; n++)
          acc[m][n] = __builtin_amdgcn_mfma_f32_16x16x32_bf16(af[m], bf[n], acc[m][n], 0, 0, 0);
    }
    __syncthreads();
  }

  // ---- epilogue ----
#pragma unroll
  for (int m = 0; m < 4; m++) {
    int lr = wr * 64 + m * 16 + (lane >> 4) * 4;
#pragma unroll
    for (int n = 0; n < 4; n++) {
      int gc = n0 + wc * 64 + n * 16 + (lane & 15);
      float bv = bias[gc];
#pragma unroll
      for (int j = 0; j < 4; j++) {
        int gi = m0 + lr + j;
        if constexpr (EXP) { if (gi >= Ne) continue; }
        float v = acc[m][n][j];
        if constexpr (MODE == 0) {
          v += bv; v = v > 0.f ? v : 0.f;
          obf[(size_t)(bases[e] + gi) * Hm + gc] = f2bf(v);
        } else if constexpr (MODE == 1) {
          int t = tlist[e * T_TOK + gi];
          float g = glist[e * T_TOK + gi];
          atomicAdd(&moe[(size_t)t * Dm + gc], g * (v + bv));
        } else if constexpr (MODE == 2) {
          v += bv; v = v > 0.f ? v : 0.f;
          obf[(size_t)gi * Hm + gc] = f2bf(v);
        } else {
          outp[(size_t)gi * Dm + gc] = moe[(size_t)gi * Dm + gc] + 0.2f * (v + bv);
        }
      }
    }
  }
}

extern "C" void kernel_launch(void* const* d_in, const int* in_sizes, int n_in,
                              void* d_out, int out_size, void* d_ws, size_t ws_size,
                              hipStream_t stream) {
  const float* x   = (const float*)d_in[0];
  const float* Wr  = (const float*)d_in[1];
  const float* W1  = (const float*)d_in[2];
  const float* b1  = (const float*)d_in[3];
  const float* W2  = (const float*)d_in[4];
  const float* b2  = (const float*)d_in[5];
  const float* sW1 = (const float*)d_in[6];
  const float* sb1 = (const float*)d_in[7];
  const float* sW2 = (const float*)d_in[8];
  const float* sb2 = (const float*)d_in[9];
  float* out = (float*)d_out;

  char* ws = (char*)d_ws;
  int*   counts = (int*)ws;                            // 64 B
  int*   bases  = (int*)(ws + 64);                     // 64 B
  int*   tlist  = (int*)(ws + 256);                    // 32 KB
  float* glist  = (float*)(ws + 256 + 32768);          // 32 KB
  float* moe    = (float*)(ws + 65792);                // 1024*768*4 = 3,145,728 B
  unsigned short* hbuf  = (unsigned short*)(ws + 65792 + 3145728);        // 2048*3072*2
  unsigned short* hsbuf = (unsigned short*)(ws + 65792 + 3145728 + 12582912); // 1024*3072*2

  (void)hipMemsetAsync(counts, 0, 64, stream);
  (void)hipMemsetAsync(moe, 0, (size_t)T_TOK * Dm * sizeof(float), stream);

  router_kernel<<<dim3(T_TOK / 4), 256, 0, stream>>>(x, Wr, counts, tlist, glist);
  prefix_kernel<<<1, 64, 0, stream>>>(counts, bases);

  moe_gemm<0><<<dim3(Hm / 128, T_TOK / 128, NE), 256, 0, stream>>>(
      x, nullptr, W1, b1, hbuf, nullptr, nullptr, counts, bases, tlist, glist);
  moe_gemm<1><<<dim3(Dm / 128, T_TOK / 128, NE), 256, 0, stream>>>(
      nullptr, hbuf, W2, b2, nullptr, moe, nullptr, counts, bases, tlist, glist);
  moe_gemm<2><<<dim3(Hm / 128, T_TOK / 128, 1), 256, 0, stream>>>(
      x, nullptr, sW1, sb1, hsbuf, nullptr, nullptr, counts, bases, tlist, glist);
  moe_gemm<3><<<dim3(Dm / 128, T_TOK / 128, 1), 256, 0, stream>>>(
      nullptr, hsbuf, sW2, sb2, nullptr, moe, out, counts, bases, tlist, glist);
}

// Round 7
// 369.209 us; speedup vs baseline: 1.3331x; 1.3331x over previous
//
#include <hip/hip_runtime.h>

#define T_TOK 1024
#define Dm 768
#define Hm 3072
#define NE 8
#define NPACK 3072      // 2048 expert-selected rows + 1024 shared rows
#define MAXTILES 32

typedef __attribute__((ext_vector_type(8))) short short8;
typedef __attribute__((ext_vector_type(4))) float f32x4;

__device__ __forceinline__ unsigned f2bf(float f) {
  unsigned u = __builtin_bit_cast(unsigned, f);
  u += 0x7fffu + ((u >> 16) & 1u);
  return u >> 16;
}
__device__ __forceinline__ unsigned pk2bf(float a, float b) {
  return f2bf(a) | (f2bf(b) << 16);
}

// ---------------- Router: logits = x @ Wr^T, top-2, softmax, compact ----------------
__global__ __launch_bounds__(256) void router_kernel(
    const float* __restrict__ x, const float* __restrict__ Wr,
    int* __restrict__ counts, int* __restrict__ tlist, float* __restrict__ glist) {
  __shared__ float sWr[NE * Dm];  // 24 KB
  for (int i = threadIdx.x; i < NE * Dm; i += 256) sWr[i] = Wr[i];
  __syncthreads();
  const int wave = threadIdx.x >> 6, lane = threadIdx.x & 63;
  const int t = blockIdx.x * 4 + wave;
  float acc[NE];
#pragma unroll
  for (int e = 0; e < NE; e++) acc[e] = 0.f;
  for (int d = lane; d < Dm; d += 64) {
    float xv = x[t * Dm + d];
#pragma unroll
    for (int e = 0; e < NE; e++) acc[e] += xv * sWr[e * Dm + d];
  }
#pragma unroll
  for (int e = 0; e < NE; e++) {
#pragma unroll
    for (int off = 32; off > 0; off >>= 1) acc[e] += __shfl_down(acc[e], off);
  }
  if (lane == 0) {
    int i0 = 0; float v0 = acc[0];
#pragma unroll
    for (int e = 1; e < NE; e++) if (acc[e] > v0) { v0 = acc[e]; i0 = e; }
    int i1 = -1; float v1 = -1e30f;
#pragma unroll
    for (int e = 0; e < NE; e++) if (e != i0 && acc[e] > v1) { v1 = acc[e]; i1 = e; }
    float g0 = 1.f / (1.f + expf(v1 - v0));
    float g1 = 1.f - g0;
    int p0 = atomicAdd(&counts[i0], 1);
    tlist[i0 * T_TOK + p0] = t; glist[i0 * T_TOK + p0] = g0;
    int p1 = atomicAdd(&counts[i1], 1);
    tlist[i1 * T_TOK + p1] = t; glist[i1 * T_TOK + p1] = g1;
  }
}

// ---------------- Prefix + tile list ----------------
__global__ void prefix_kernel(const int* __restrict__ counts, int* __restrict__ bases,
                              int* __restrict__ ntiles, int2* __restrict__ tiles) {
  if (threadIdx.x == 0) {
    int s = 0;
    for (int e = 0; e < NE; e++) { bases[e] = s; s += counts[e]; }
    bases[NE] = s;  // == 2048, shared rows start here
    int nt = 0;
    for (int e = 0; e <= NE; e++) {
      int Ne = (e < NE) ? counts[e] : T_TOK;
      for (int m0 = 0; m0 < Ne && nt < MAXTILES; m0 += 128) tiles[nt++] = make_int2(e, m0);
    }
    *ntiles = nt;
  }
}

// ---------------- Packed-M bf16 MFMA GEMM, 128x128 tile, BK=64, 8 waves ----------------
// MODE 0: h[prow] = relu(gather(x) @ W1^T + b1)      K=768,        N=3072 -> hbuf bf16
// MODE 1: out[tok] += gate*(h[prow] @ W2^T + b2)     K=1536/chunk, N=768  -> atomicAdd f32
template <int MODE>
__global__ __launch_bounds__(512) void moe_gemm(
    const float* __restrict__ x,
    const float* __restrict__ W1, const float* __restrict__ b1,
    const float* __restrict__ sW1, const float* __restrict__ sb1,
    const float* __restrict__ W2, const float* __restrict__ b2,
    const float* __restrict__ sW2, const float* __restrict__ sb2,
    unsigned short* __restrict__ hbuf, float* __restrict__ outp,
    const int* __restrict__ counts, const int* __restrict__ bases,
    const int* __restrict__ ntiles, const int2* __restrict__ tiles,
    const int* __restrict__ tlist, const float* __restrict__ glist) {
  const int ti = blockIdx.y;
  if (ti >= *ntiles) return;
  const int2 tl = tiles[ti];
  const int e = tl.x, m0 = tl.y;
  const int Ne = (e < NE) ? counts[e] : T_TOK;
  const int pbase = bases[e];
  const int n0 = blockIdx.x * 128;

  constexpr int Kfull = (MODE == 0) ? Dm : Hm;        // stride of B rows
  constexpr int KC    = (MODE == 0) ? Dm : (Hm / 2);  // K span per block
  constexpr int NK    = KC / 64;
  const int kbase = (MODE == 0) ? 0 : (blockIdx.z * KC);

  const float* Bw;
  const float* bias;
  if constexpr (MODE == 0) {
    Bw   = (e < NE) ? W1 + (size_t)e * Hm * Dm : sW1;
    bias = (e < NE) ? b1 + (size_t)e * Hm : sb1;
  } else {
    Bw   = (e < NE) ? W2 + (size_t)e * Dm * Hm : sW2;
    bias = (e < NE) ? b2 + (size_t)e * Dm : sb2;
  }

  __shared__ unsigned short sA[128][72];
  __shared__ unsigned short sB[128][72];

  const int tid = threadIdx.x;
  const int lane = tid & 63;
  const int wid = tid >> 6;          // 0..7
  const int wr = wid >> 2;           // 0..1 -> 64 rows
  const int wc = wid & 3;            // 0..3 -> 32 cols

  // ---- staging pointers (col offset folded in) ----
  const float* aPtrF[4];
  const unsigned short* aPtrH[2];
  if constexpr (MODE == 0) {
#pragma unroll
    for (int c = 0; c < 4; c++) {
      int gi = m0 + c * 32 + (tid >> 4);
      int si = gi < Ne ? gi : Ne - 1;
      int tok = (e < NE) ? tlist[e * T_TOK + si] : si;
      aPtrF[c] = x + (size_t)tok * Dm + (tid & 15) * 4;
    }
  } else {
#pragma unroll
    for (int c = 0; c < 2; c++) {
      int prow = pbase + m0 + c * 64 + (tid >> 3);
      if (prow >= NPACK) prow = NPACK - 1;
      aPtrH[c] = hbuf + (size_t)prow * Hm + kbase + (tid & 7) * 8;
    }
  }
  const float* bPtrF[4];
#pragma unroll
  for (int c = 0; c < 4; c++) {
    int nrow = n0 + c * 32 + (tid >> 4);
    bPtrF[c] = Bw + (size_t)nrow * Kfull + kbase + (tid & 15) * 4;
  }

  f32x4 acc[4][2];
#pragma unroll
  for (int m = 0; m < 4; m++)
#pragma unroll
    for (int n = 0; n < 2; n++) acc[m][n] = (f32x4)0.0f;

  const int rF = tid >> 4;        // f32 staging row base (0..31)
  const int cF = (tid & 15) * 4;  // f32 staging col (shorts)
  const int rH = tid >> 3;        // bf16 staging row base (0..63)
  const int cH = (tid & 7) * 8;   // bf16 staging col
  const int frow = lane & 15;
  const int fk = (lane >> 4) * 8;

  // ---- staging registers (2-deep: next K-tile loads overlap MFMA) ----
  float4 aF[4], bF[4];
  uint4 aH[2];

  if constexpr (MODE == 0) {
#pragma unroll
    for (int c = 0; c < 4; c++) aF[c] = *(const float4*)(aPtrF[c]);
  } else {
#pragma unroll
    for (int c = 0; c < 2; c++) aH[c] = *(const uint4*)(aPtrH[c]);
  }
#pragma unroll
  for (int c = 0; c < 4; c++) bF[c] = *(const float4*)(bPtrF[c]);

  for (int ks = 0; ks < NK; ks++) {
    // ---- write staged regs -> LDS (f32 -> bf16 convert) ----
    if constexpr (MODE == 0) {
#pragma unroll
      for (int c = 0; c < 4; c++) {
        *(uint2*)&sA[c * 32 + rF][cF] =
            make_uint2(pk2bf(aF[c].x, aF[c].y), pk2bf(aF[c].z, aF[c].w));
      }
    } else {
#pragma unroll
      for (int c = 0; c < 2; c++) *(uint4*)&sA[c * 64 + rH][cH] = aH[c];
    }
#pragma unroll
    for (int c = 0; c < 4; c++) {
      *(uint2*)&sB[c * 32 + rF][cF] =
          make_uint2(pk2bf(bF[c].x, bF[c].y), pk2bf(bF[c].z, bF[c].w));
    }
    __syncthreads();

    // ---- issue next k-tile's global loads (overlap with MFMA below) ----
    if (ks + 1 < NK) {
      int ko = (ks + 1) * 64;
      if constexpr (MODE == 0) {
#pragma unroll
        for (int c = 0; c < 4; c++) aF[c] = *(const float4*)(aPtrF[c] + ko);
      } else {
#pragma unroll
        for (int c = 0; c < 2; c++) aH[c] = *(const uint4*)(aPtrH[c] + ko);
      }
#pragma unroll
      for (int c = 0; c < 4; c++) bF[c] = *(const float4*)(bPtrF[c] + ko);
    }

    // ---- MFMA over BK=64 ----
#pragma unroll
    for (int kk = 0; kk < 2; kk++) {
      short8 af[4], bfr[2];
#pragma unroll
      for (int m = 0; m < 4; m++)
        af[m] = *(const short8*)&sA[wr * 64 + m * 16 + frow][kk * 32 + fk];
#pragma unroll
      for (int n = 0; n < 2; n++)
        bfr[n] = *(const short8*)&sB[wc * 32 + n * 16 + frow][kk * 32 + fk];
#pragma unroll
      for (int m = 0; m < 4; m++)
#pragma unroll
        for (int n = 0; n < 2; n++)
          acc[m][n] = __builtin_amdgcn_mfma_f32_16x16x32_bf16(af[m], bfr[n], acc[m][n], 0, 0, 0);
    }
    __syncthreads();
  }

  // ---- epilogue ----
#pragma unroll
  for (int m = 0; m < 4; m++) {
    int lr = wr * 64 + m * 16 + (lane >> 4) * 4;
#pragma unroll
    for (int n = 0; n < 2; n++) {
      int gc = n0 + wc * 32 + n * 16 + (lane & 15);
      float bv = bias[gc];
#pragma unroll
      for (int j = 0; j < 4; j++) {
        int gi = m0 + lr + j;
        if (gi >= Ne) continue;
        float v = acc[m][n][j];
        if constexpr (MODE == 0) {
          v += bv;
          v = v > 0.f ? v : 0.f;
          hbuf[(size_t)(pbase + gi) * Hm + gc] = (unsigned short)f2bf(v);
        } else {
          int t; float g;
          if (e < NE) { t = tlist[e * T_TOK + gi]; g = glist[e * T_TOK + gi]; }
          else        { t = gi; g = 0.2f; }
          float add = g * (v + (kbase == 0 ? bv : 0.f));
          atomicAdd(&outp[(size_t)t * Dm + gc], add);
        }
      }
    }
  }
}

extern "C" void kernel_launch(void* const* d_in, const int* in_sizes, int n_in,
                              void* d_out, int out_size, void* d_ws, size_t ws_size,
                              hipStream_t stream) {
  const float* x   = (const float*)d_in[0];
  const float* Wr  = (const float*)d_in[1];
  const float* W1  = (const float*)d_in[2];
  const float* b1  = (const float*)d_in[3];
  const float* W2  = (const float*)d_in[4];
  const float* b2  = (const float*)d_in[5];
  const float* sW1 = (const float*)d_in[6];
  const float* sb1 = (const float*)d_in[7];
  const float* sW2 = (const float*)d_in[8];
  const float* sb2 = (const float*)d_in[9];
  float* out = (float*)d_out;

  char* ws = (char*)d_ws;
  int*    counts  = (int*)(ws + 0);            // 128 B
  int*    bases   = (int*)(ws + 128);          // 64 B
  int*    ntiles  = (int*)(ws + 192);          // 64 B
  int2*   tiles   = (int2*)(ws + 256);         // 512 B
  int*    tlist   = (int*)(ws + 768);          // 32 KB -> ends 33536
  float*  glist   = (float*)(ws + 33536);      // 32 KB -> ends 66304
  unsigned short* hbuf = (unsigned short*)(ws + 66304);  // 3072*3072*2 = 18,874,368
  // total ws usage ~18.9 MB (round-1 kernel proved ~22 MB fits)

  (void)hipMemsetAsync(counts, 0, 128, stream);
  (void)hipMemsetAsync(out, 0, (size_t)T_TOK * Dm * sizeof(float), stream);

  router_kernel<<<dim3(T_TOK / 4), 256, 0, stream>>>(x, Wr, counts, tlist, glist);
  prefix_kernel<<<1, 64, 0, stream>>>(counts, bases, ntiles, tiles);

  // GEMM1: packed rows (experts + shared) x W1^T, relu, -> hbuf bf16
  moe_gemm<0><<<dim3(Hm / 128, MAXTILES, 1), 512, 0, stream>>>(
      x, W1, b1, sW1, sb1, W2, b2, sW2, sb2, hbuf, out,
      counts, bases, ntiles, tiles, tlist, glist);
  // GEMM2: hbuf x W2^T, split-K=2, gate+bias in epilogue, atomicAdd -> out
  moe_gemm<1><<<dim3(Dm / 128, MAXTILES, 2), 512, 0, stream>>>(
      x, W1, b1, sW1, sb1, W2, b2, sW2, sb2, hbuf, out,
      counts, bases, ntiles, tiles, tlist, glist);
}